// Round 7
// baseline (186.190 us; speedup 1.0000x reference)
//
#include <hip/hip_runtime.h>
#include <hip/hip_bf16.h>
#include <stdint.h>

#define M_TOT 16384
#define N_TOT 2048
#define K_TOT 2048
#define NT 32            // K-tiles of BK=64

typedef __attribute__((ext_vector_type(8))) short bf16x8;
typedef __attribute__((ext_vector_type(4))) float f32x4;
typedef __attribute__((ext_vector_type(16))) float f32x16;

__device__ __forceinline__ ushort f32_to_bf16_rne(float f) {
    uint32_t u = __float_as_uint(f);
    uint32_t r = (u + 0x7fffu + ((u >> 16) & 1u)) >> 16;
    return (ushort)r;
}

__device__ __forceinline__ void async_copy16(const void* gptr, void* lptr) {
    __builtin_amdgcn_global_load_lds(
        (const __attribute__((address_space(1))) uint32_t*)gptr,
        (__attribute__((address_space(3))) uint32_t*)lptr,
        16, 0, 0);
}

// ---------------------------------------------------------------------------
// Fake-quantize x: per (row, 32-col) block, symmetric int8 -> bf16.
// ---------------------------------------------------------------------------
__global__ void quant_x_kernel(const float* __restrict__ x, ushort* __restrict__ qx) {
    const int tid = blockIdx.x * 256 + threadIdx.x;
    const float4 v = ((const float4*)x)[tid];
    float m = fmaxf(fmaxf(fabsf(v.x), fabsf(v.y)), fmaxf(fabsf(v.z), fabsf(v.w)));
    m = fmaxf(m, __shfl_xor(m, 1));
    m = fmaxf(m, __shfl_xor(m, 2));
    m = fmaxf(m, __shfl_xor(m, 4));
    const float s = (m > 0.f) ? (m / 127.f) : 1.f;
    const float q0 = fminf(fmaxf(rintf(v.x / s), -127.f), 127.f) * s;
    const float q1 = fminf(fmaxf(rintf(v.y / s), -127.f), 127.f) * s;
    const float q2 = fminf(fmaxf(rintf(v.z / s), -127.f), 127.f) * s;
    const float q3 = fminf(fmaxf(rintf(v.w / s), -127.f), 127.f) * s;
    ushort4 r;
    r.x = f32_to_bf16_rne(q0);
    r.y = f32_to_bf16_rne(q1);
    r.z = f32_to_bf16_rne(q2);
    r.w = f32_to_bf16_rne(q3);
    ((ushort4*)qx)[tid] = r;
}

// ---------------------------------------------------------------------------
// Fake-quantize weight (kept [Dout][Din] == B^T layout). 32x32 blocks.
// ---------------------------------------------------------------------------
__global__ void quant_w_kernel(const float* __restrict__ w, ushort* __restrict__ qw) {
    const int gtid = blockIdx.x * 256 + threadIdx.x;
    const int wid  = gtid >> 6;
    const int lane = gtid & 63;
    const int tn = wid >> 6;
    const int tk = wid & 63;
    const int row = tn * 32 + (lane >> 1);
    const int col = tk * 32 + ((lane & 1) << 4);
    const float* p = w + (size_t)row * K_TOT + col;
    const float4 v0 = ((const float4*)p)[0];
    const float4 v1 = ((const float4*)p)[1];
    const float4 v2 = ((const float4*)p)[2];
    const float4 v3 = ((const float4*)p)[3];
    float m = 0.f;
#define MAX4(V) m = fmaxf(m, fmaxf(fmaxf(fabsf(V.x), fabsf(V.y)), fmaxf(fabsf(V.z), fabsf(V.w))));
    MAX4(v0) MAX4(v1) MAX4(v2) MAX4(v3)
#undef MAX4
    #pragma unroll
    for (int off = 1; off < 64; off <<= 1) m = fmaxf(m, __shfl_xor(m, off));
    const float s = (m > 0.f) ? (m / 127.f) : 1.f;
    float vv[16] = {v0.x, v0.y, v0.z, v0.w, v1.x, v1.y, v1.z, v1.w,
                    v2.x, v2.y, v2.z, v2.w, v3.x, v3.y, v3.z, v3.w};
    union { ushort us[16]; uint4 q[2]; } o;
    #pragma unroll
    for (int i = 0; i < 16; ++i) {
        const float q = fminf(fmaxf(rintf(vv[i] / s), -127.f), 127.f) * s;
        o.us[i] = f32_to_bf16_rne(q);
    }
    uint4* dst = (uint4*)(qw + (size_t)row * K_TOT + col);
    dst[0] = o.q[0];
    dst[1] = o.q[1];
}

// ---------------------------------------------------------------------------
// 256x256 bf16 GEMM — R5 flattened-read schedule, 32x32x16 MFMA shape.
// MFMA floor 2560 -> 2048 cyc/tile/CU; LDS traffic/pattern unchanged.
// Per wave: output 128x64 = 4 m-groups(32r) x 2 n-groups(32c); phase q does
// m-group q: 8 MFMA (2 n x 4 k-slices).  Waits: p0 lgkm(4) leaves afY;
// p1 lgkm(4) leaves afX; p2 lgkm(4) leaves afY; p3 lgkm(0).
// vmcnt(4)@p3 drains B(t+1)+A(t+1), keeps B(t+2) in flight.  2 barriers/tile.
// ---------------------------------------------------------------------------
#define LDSA(tb, row, colus) \
    (*(const bf16x8*)&As[tb][row][(colus) ^ (((row) & 7) << 3)])
#define LDSB(tb, row, colus) \
    (*(const bf16x8*)&Bs[tb][row][(colus) ^ (((row) & 7) << 3)])

#define STAGE_A(tb, hh, li, tt)                                                          \
    async_copy16(Agbase + (size_t)((hh) * 128 + (li) * 64) * K_TOT + (size_t)(tt) * 64,  \
                 (char*)&As[0][0][0] + (tb) * 32768 + (hh) * 16384 + (li) * 8192 + (wv << 10));
#define STAGE_B(tb, hh, li, tt)                                                          \
    async_copy16(Bgbase + (size_t)((hh) * 128 + (li) * 64) * K_TOT + (size_t)(tt) * 64,  \
                 (char*)&Bs[0][0][0] + (tb) * 32768 + (hh) * 16384 + (li) * 8192 + (wv << 10));
#define STAGE_A2(tb, hh, tt)  { STAGE_A(tb, hh, 0, tt) STAGE_A(tb, hh, 1, tt) }
#define STAGE_B2(tb, hh, tt)  { STAGE_B(tb, hh, 0, tt) STAGE_B(tb, hh, 1, tt) }

#define WAITLGKM4 { asm volatile("s_waitcnt lgkmcnt(4)" ::: "memory"); __builtin_amdgcn_sched_barrier(0); }
#define WAITLGKM0 { asm volatile("s_waitcnt lgkmcnt(0)" ::: "memory"); __builtin_amdgcn_sched_barrier(0); }

// 4 A-fragments of m-group q (rows q*32 + (lane&31)), k-slices 0..3
#define RD_AF(DST, tb, q) {                                   \
    DST[0] = LDSA(tb, ab32 + (q) * 32,  0 + kb8);             \
    DST[1] = LDSA(tb, ab32 + (q) * 32, 16 + kb8);             \
    DST[2] = LDSA(tb, ab32 + (q) * 32, 32 + kb8);             \
    DST[3] = LDSA(tb, ab32 + (q) * 32, 48 + kb8); }

// 8 B-fragments (2 n-groups x 4 k-slices)
#define RD_BG(tb) {                                                           \
    _Pragma("unroll")                                                         \
    for (int n = 0; n < 2; ++n) {                                             \
        const int bb = bb32 + n * 32;                                         \
        _Pragma("unroll")                                                     \
        for (int ks = 0; ks < 4; ++ks)                                        \
            bg[n][ks] = LDSB(tb, bb, ks * 16 + kb8);                          \
    } }

#define MFMA_PH(q, AF)                                                                    \
    __builtin_amdgcn_s_setprio(1);                                                        \
    _Pragma("unroll")                                                                     \
    for (int ks = 0; ks < 4; ++ks) {                                                      \
        acc[q][0] = __builtin_amdgcn_mfma_f32_32x32x16_bf16(AF[ks], bg[0][ks], acc[q][0], 0, 0, 0); \
        acc[q][1] = __builtin_amdgcn_mfma_f32_32x32x16_bf16(AF[ks], bg[1][ks], acc[q][1], 0, 0, 0); \
    }                                                                                     \
    __builtin_amdgcn_s_setprio(0);

// One K-tile.  STA: stage A(t+1); STB: stage B(t+2); VMC: 4 / 0 / -1 (skip).
#define TILE_BODY(tb, t, STA, STB, VMC)                                                   \
  {                                                                                       \
    /* -- p0: afX(q0) + bg(8) + afY(q1); stage A(t+1)h0; drain afX+bg -- */               \
    RD_AF(afX, tb, 0)                                                                     \
    RD_BG(tb)                                                                             \
    RD_AF(afY, tb, 1)                                                                     \
    if (STA) STAGE_A2(tb ^ 1, 0, (t) + 1)                                                 \
    WAITLGKM4                                                                             \
    MFMA_PH(0, afX)                                                                       \
    /* -- p1: afX(q2); stage A(t+1)h1; drain afY -- */                                    \
    RD_AF(afX, tb, 2)                                                                     \
    if (STA) STAGE_A2(tb ^ 1, 1, (t) + 1)                                                 \
    WAITLGKM4                                                                             \
    MFMA_PH(1, afY)                                                                       \
    __builtin_amdgcn_s_barrier();  /* all bg reads served -> B-stage safe */              \
    /* -- p2: afY(q3); stage B(t+2)h0; drain afX -- */                                    \
    RD_AF(afY, tb, 3)                                                                     \
    if (STB) STAGE_B2(tb, 0, (t) + 2)                                                     \
    WAITLGKM4                                                                             \
    MFMA_PH(2, afX)                                                                       \
    /* -- p3: stage B(t+2)h1; drain afY; counted vmcnt -- */                              \
    if (STB) STAGE_B2(tb, 1, (t) + 2)                                                     \
    WAITLGKM0                                                                             \
    MFMA_PH(3, afY)                                                                       \
    if ((VMC) == 4)      { asm volatile("s_waitcnt vmcnt(4)" ::: "memory"); }             \
    else if ((VMC) == 0) { asm volatile("s_waitcnt vmcnt(0)" ::: "memory"); }             \
    __builtin_amdgcn_s_barrier();  /* staged A(t+1)/B(t+1) visible */                     \
  }

__global__ __launch_bounds__(512, 2) void gemm_pipe32_kernel(
    const ushort* __restrict__ A,    // [M][K] bf16 bits
    const ushort* __restrict__ Bt,   // [N][K] bf16 bits
    const float* __restrict__ bias,  // [N]
    float* __restrict__ C) {         // [M][N]

    __shared__ ushort As[2][256][64];   // 64 KB
    __shared__ ushort Bs[2][256][64];   // 64 KB

    const int tid  = threadIdx.x;
    const int lane = tid & 63;
    const int wv   = tid >> 6;          // wave 0..7
    const int wmr  = wv >> 2;           // 0..1  (M)
    const int wcn  = wv & 3;            // 0..3  (N)
    const int l31  = lane & 31;
    const int kb8  = (lane >> 5) << 3;  // k-offset within 16-slice (ushorts)

    // bijective XCD swizzle (nwg = 512)
    const int nbn  = N_TOT / 256;                 // 8
    const int nwg  = (M_TOT / 256) * nbn;         // 512
    const int cpx  = nwg >> 3;
    const int swz  = (blockIdx.x & 7) * cpx + (blockIdx.x >> 3);
    const int brow = (swz / nbn) * 256;
    const int bcol = (swz % nbn) * 256;

    // staging: thread -> row tid>>3 of each 64-row group, 16B at pre-swizzled col
    const int srow = tid >> 3;
    const int scol = (((tid & 7) ^ (srow & 7)) << 3);
    const ushort* Agbase = A  + (size_t)(brow + srow) * K_TOT + scol;
    const ushort* Bgbase = Bt + (size_t)(bcol + srow) * K_TOT + scol;

    const int ab32 = wmr * 128 + l31;   // wave's A row base (+q*32)
    const int bb32 = wcn * 64 + l31;    // wave's B row base (+n*32)

    f32x16 acc[4][2];
    #pragma unroll
    for (int i = 0; i < 4; ++i)
        #pragma unroll
        for (int j = 0; j < 2; ++j)
            #pragma unroll
            for (int e = 0; e < 16; ++e) acc[i][j][e] = 0.f;

    // ---- prologue: A(0)+B(0)+B(1); vmcnt(4) keeps B(1) in flight ----
    STAGE_A2(0, 0, 0) STAGE_A2(0, 1, 0)
    STAGE_B2(0, 0, 0) STAGE_B2(0, 1, 0)
    STAGE_B2(1, 0, 1) STAGE_B2(1, 1, 1)
    asm volatile("s_waitcnt vmcnt(4)" ::: "memory");
    __builtin_amdgcn_s_barrier();

    bf16x8 afX[4], afY[4];
    bf16x8 bg[2][4];

    for (int t = 0; t < NT - 2; t += 2) {
        TILE_BODY(0, t,     1, 1, 4)
        TILE_BODY(1, t + 1, 1, 1, 4)
    }
    TILE_BODY(0, NT - 2, 1, 0, 0)    // stage A(31) only; drain all
    TILE_BODY(1, NT - 1, 0, 0, -1)   // pure compute

    // ---- epilogue: bias + store (32x32 C/D: col=lane&31, row=(reg&3)+8*(reg>>2)+4*(lane>>5))
    const int rb4 = (lane >> 5) * 4;
    #pragma unroll
    for (int q = 0; q < 4; ++q) {
        const int row0 = brow + wmr * 128 + q * 32 + rb4;
        #pragma unroll
        for (int n = 0; n < 2; ++n) {
            const int col = bcol + wcn * 64 + n * 32 + l31;
            const float bv = bias[col];
            #pragma unroll
            for (int reg = 0; reg < 16; ++reg) {
                const int row = row0 + (reg & 3) + 8 * (reg >> 2);
                C[(size_t)row * N_TOT + col] = acc[q][n][reg] + bv;
            }
        }
    }
}

extern "C" void kernel_launch(void* const* d_in, const int* in_sizes, int n_in,
                              void* d_out, int out_size, void* d_ws, size_t ws_size,
                              hipStream_t stream) {
    const float* x    = (const float*)d_in[0];   // [4,4096,2048]
    const float* wgt  = (const float*)d_in[1];   // [2048,2048]
    const float* bias = (const float*)d_in[2];   // [2048]
    float* out = (float*)d_out;                  // [4,4096,2048]

    ushort* qx = (ushort*)d_ws;                          // 64 MB
    ushort* qw = qx + (size_t)M_TOT * K_TOT;             // 8 MB

    quant_x_kernel<<<(M_TOT * K_TOT / 4) / 256, 256, 0, stream>>>(x, qx);
    quant_w_kernel<<<(64 * 64 * 64) / 256, 256, 0, stream>>>(wgt, qw);
    gemm_pipe32_kernel<<<(M_TOT / 256) * (N_TOT / 256), 512, 0, stream>>>(qx, qw, bias, out);
}

// Round 8
// 170.398 us; speedup vs baseline: 1.0927x; 1.0927x over previous
//
#include <hip/hip_runtime.h>
#include <hip/hip_bf16.h>
#include <stdint.h>

#define M_TOT 16384
#define N_TOT 2048
#define K_TOT 2048
#define NT 32            // K-tiles of BK=64

typedef __attribute__((ext_vector_type(8))) short bf16x8;
typedef __attribute__((ext_vector_type(4))) float f32x4;

__device__ __forceinline__ ushort f32_to_bf16_rne(float f) {
    uint32_t u = __float_as_uint(f);
    uint32_t r = (u + 0x7fffu + ((u >> 16) & 1u)) >> 16;
    return (ushort)r;
}

__device__ __forceinline__ void async_copy16(const void* gptr, void* lptr) {
    __builtin_amdgcn_global_load_lds(
        (const __attribute__((address_space(1))) uint32_t*)gptr,
        (__attribute__((address_space(3))) uint32_t*)lptr,
        16, 0, 0);
}

// ---------------------------------------------------------------------------
// Fake-quantize x: per (row, 32-col) block, symmetric int8 -> bf16.
// ---------------------------------------------------------------------------
__global__ void quant_x_kernel(const float* __restrict__ x, ushort* __restrict__ qx) {
    const int tid = blockIdx.x * 256 + threadIdx.x;
    const float4 v = ((const float4*)x)[tid];
    float m = fmaxf(fmaxf(fabsf(v.x), fabsf(v.y)), fmaxf(fabsf(v.z), fabsf(v.w)));
    m = fmaxf(m, __shfl_xor(m, 1));
    m = fmaxf(m, __shfl_xor(m, 2));
    m = fmaxf(m, __shfl_xor(m, 4));
    const float s = (m > 0.f) ? (m / 127.f) : 1.f;
    const float q0 = fminf(fmaxf(rintf(v.x / s), -127.f), 127.f) * s;
    const float q1 = fminf(fmaxf(rintf(v.y / s), -127.f), 127.f) * s;
    const float q2 = fminf(fmaxf(rintf(v.z / s), -127.f), 127.f) * s;
    const float q3 = fminf(fmaxf(rintf(v.w / s), -127.f), 127.f) * s;
    ushort4 r;
    r.x = f32_to_bf16_rne(q0);
    r.y = f32_to_bf16_rne(q1);
    r.z = f32_to_bf16_rne(q2);
    r.w = f32_to_bf16_rne(q3);
    ((ushort4*)qx)[tid] = r;
}

// ---------------------------------------------------------------------------
// Fake-quantize weight (kept [Dout][Din] == B^T layout). 32x32 blocks.
// ---------------------------------------------------------------------------
__global__ void quant_w_kernel(const float* __restrict__ w, ushort* __restrict__ qw) {
    const int gtid = blockIdx.x * 256 + threadIdx.x;
    const int wid  = gtid >> 6;
    const int lane = gtid & 63;
    const int tn = wid >> 6;
    const int tk = wid & 63;
    const int row = tn * 32 + (lane >> 1);
    const int col = tk * 32 + ((lane & 1) << 4);
    const float* p = w + (size_t)row * K_TOT + col;
    const float4 v0 = ((const float4*)p)[0];
    const float4 v1 = ((const float4*)p)[1];
    const float4 v2 = ((const float4*)p)[2];
    const float4 v3 = ((const float4*)p)[3];
    float m = 0.f;
#define MAX4(V) m = fmaxf(m, fmaxf(fmaxf(fabsf(V.x), fabsf(V.y)), fmaxf(fabsf(V.z), fabsf(V.w))));
    MAX4(v0) MAX4(v1) MAX4(v2) MAX4(v3)
#undef MAX4
    #pragma unroll
    for (int off = 1; off < 64; off <<= 1) m = fmaxf(m, __shfl_xor(m, off));
    const float s = (m > 0.f) ? (m / 127.f) : 1.f;
    float vv[16] = {v0.x, v0.y, v0.z, v0.w, v1.x, v1.y, v1.z, v1.w,
                    v2.x, v2.y, v2.z, v2.w, v3.x, v3.y, v3.z, v3.w};
    union { ushort us[16]; uint4 q[2]; } o;
    #pragma unroll
    for (int i = 0; i < 16; ++i) {
        const float q = fminf(fmaxf(rintf(vv[i] / s), -127.f), 127.f) * s;
        o.us[i] = f32_to_bf16_rne(q);
    }
    uint4* dst = (uint4*)(qw + (size_t)row * K_TOT + col);
    dst[0] = o.q[0];
    dst[1] = o.q[1];
}

// ---------------------------------------------------------------------------
// 256x256 bf16 GEMM (16x16x32 MFMA), R5 schedule + bg-late refinement:
//   bg(t+1) is read at END of p3 (after MFMA q3; WAR on bg regs pins it),
//   draining during the vmcnt+barrier+p0-issue window, so p0's lgkm(4)
//   covers only old reads.  vmcnt(4)@p1 AFTER MFMA(q1) drains B(t+1);
//   vmcnt(4)@p3 drains A(t+1), keeps B(t+2) in flight.  2 barriers/tile.
// lgkm trace: p0 wait drains bg8+afX4 (leaves afY); p1 drains afY (leaves
// afX); p2 drains afX (leaves afY); p3 lgkm(0) drains afY; then bg8 issue.
// ---------------------------------------------------------------------------
#define LDSA(tb, row, colus) \
    (*(const bf16x8*)&As[tb][row][(colus) ^ (((row) & 7) << 3)])
#define LDSB(tb, row, colus) \
    (*(const bf16x8*)&Bs[tb][row][(colus) ^ (((row) & 7) << 3)])

#define STAGE_A(tb, hh, li, tt)                                                          \
    async_copy16(Agbase + (size_t)((hh) * 128 + (li) * 64) * K_TOT + (size_t)(tt) * 64,  \
                 (char*)&As[0][0][0] + (tb) * 32768 + (hh) * 16384 + (li) * 8192 + (wv << 10));
#define STAGE_B(tb, hh, li, tt)                                                          \
    async_copy16(Bgbase + (size_t)((hh) * 128 + (li) * 64) * K_TOT + (size_t)(tt) * 64,  \
                 (char*)&Bs[0][0][0] + (tb) * 32768 + (hh) * 16384 + (li) * 8192 + (wv << 10));
#define STAGE_A2(tb, hh, tt)  { STAGE_A(tb, hh, 0, tt) STAGE_A(tb, hh, 1, tt) }
#define STAGE_B2(tb, hh, tt)  { STAGE_B(tb, hh, 0, tt) STAGE_B(tb, hh, 1, tt) }

#define WAITLGKM4 { asm volatile("s_waitcnt lgkmcnt(4)" ::: "memory"); __builtin_amdgcn_sched_barrier(0); }
#define WAITLGKM0 { asm volatile("s_waitcnt lgkmcnt(0)" ::: "memory"); __builtin_amdgcn_sched_barrier(0); }

// read the 4 A-fragments of row-pair q (rows q*32, q*32+16; k lo/hi halves)
#define RD_AF(DST, tb, q) {                                   \
    DST[0] = LDSA(tb, ab + (q) * 32,      h8);                \
    DST[1] = LDSA(tb, ab + (q) * 32,      32 + h8);           \
    DST[2] = LDSA(tb, ab + (q) * 32 + 16, h8);                \
    DST[3] = LDSA(tb, ab + (q) * 32 + 16, 32 + h8); }

#define RD_BG(tb) {                                                           \
    _Pragma("unroll")                                                         \
    for (int j = 0; j < 4; ++j) {                                             \
        const int bb = wcn * 64 + j * 16 + r;                                 \
        bg[j][0] = LDSB(tb, bb, h8);  bg[j][1] = LDSB(tb, bb, 32 + h8);       \
    } }

#define MFMA_PH(i0, AF)                                                                   \
    __builtin_amdgcn_s_setprio(1);                                                        \
    _Pragma("unroll")                                                                     \
    for (int j = 0; j < 4; ++j) {                                                         \
        acc[i0][j]     = __builtin_amdgcn_mfma_f32_16x16x32_bf16(AF[0], bg[j][0], acc[i0][j], 0, 0, 0);     \
        acc[i0][j]     = __builtin_amdgcn_mfma_f32_16x16x32_bf16(AF[1], bg[j][1], acc[i0][j], 0, 0, 0);     \
        acc[(i0)+1][j] = __builtin_amdgcn_mfma_f32_16x16x32_bf16(AF[2], bg[j][0], acc[(i0)+1][j], 0, 0, 0); \
        acc[(i0)+1][j] = __builtin_amdgcn_mfma_f32_16x16x32_bf16(AF[3], bg[j][1], acc[(i0)+1][j], 0, 0, 0); \
    }                                                                                     \
    __builtin_amdgcn_s_setprio(0);

// One K-tile.  STA: stage A(t+1); STB: stage B(t+2); RDBG: read bg(t+1) at p3;
// VM1/VM3: vmcnt at p1 (drain B(t+1)) / p3 (drain A(t+1)); -1 = skip.
#define TILE_BODY(tb, t, STA, STB, RDBG, VM1, VM3)                                        \
  {                                                                                       \
    /* -- p0: issue afX(q0)+afY(q1); stage A(t+1)h0; drain bg8+afX -- */                  \
    RD_AF(afX, tb, 0)                                                                     \
    __builtin_amdgcn_sched_barrier(0);                                                    \
    RD_AF(afY, tb, 1)                                                                     \
    if (STA) STAGE_A2(tb ^ 1, 0, (t) + 1)                                                 \
    WAITLGKM4                                                                             \
    MFMA_PH(0, afX)                                                                       \
    /* -- p1: issue afX(q2); stage A(t+1)h1; drain afY; vmcnt; barrier -- */              \
    RD_AF(afX, tb, 2)                                                                     \
    if (STA) STAGE_A2(tb ^ 1, 1, (t) + 1)                                                 \
    WAITLGKM4                                                                             \
    MFMA_PH(2, afY)                                                                       \
    if ((VM1) == 4) { asm volatile("s_waitcnt vmcnt(4)" ::: "memory"); }                  \
    else if ((VM1) == 0) { asm volatile("s_waitcnt vmcnt(0)" ::: "memory"); }             \
    __builtin_amdgcn_s_barrier();  /* Bs WAR fence + B(t+1) collectively visible */       \
    /* -- p2: issue afY(q3); stage B(t+2)h0; drain afX -- */                              \
    RD_AF(afY, tb, 3)                                                                     \
    if (STB) STAGE_B2(tb, 0, (t) + 2)                                                     \
    WAITLGKM4                                                                             \
    MFMA_PH(4, afX)                                                                       \
    /* -- p3: stage B(t+2)h1; drain afY; MFMA; bg(t+1); vmcnt; barrier -- */              \
    if (STB) STAGE_B2(tb, 1, (t) + 2)                                                     \
    WAITLGKM0                                                                             \
    MFMA_PH(6, afY)                                                                       \
    if (RDBG) RD_BG((tb) ^ 1)   /* drains under vmcnt+barrier+next-p0 issue */            \
    if ((VM3) == 4) { asm volatile("s_waitcnt vmcnt(4)" ::: "memory"); }                  \
    else if ((VM3) == 0) { asm volatile("s_waitcnt vmcnt(0)" ::: "memory"); }             \
    __builtin_amdgcn_s_barrier();  /* A(t+1) collectively visible */                      \
  }

__global__ __launch_bounds__(512, 2) void gemm_pipe4_kernel(
    const ushort* __restrict__ A,    // [M][K] bf16 bits
    const ushort* __restrict__ Bt,   // [N][K] bf16 bits
    const float* __restrict__ bias,  // [N]
    float* __restrict__ C) {         // [M][N]

    __shared__ ushort As[2][256][64];   // 64 KB
    __shared__ ushort Bs[2][256][64];   // 64 KB

    const int tid  = threadIdx.x;
    const int lane = tid & 63;
    const int wv   = tid >> 6;          // wave 0..7
    const int wmr  = wv >> 2;           // 0..1  (M)
    const int wcn  = wv & 3;            // 0..3  (N)
    const int r    = lane & 15;
    const int h8   = (lane >> 4) << 3;  // 0,8,16,24 (ushort col of k-frag)

    // bijective XCD swizzle (nwg = 512)
    const int nbn  = N_TOT / 256;                 // 8
    const int nwg  = (M_TOT / 256) * nbn;         // 512
    const int cpx  = nwg >> 3;
    const int swz  = (blockIdx.x & 7) * cpx + (blockIdx.x >> 3);
    const int brow = (swz / nbn) * 256;
    const int bcol = (swz % nbn) * 256;

    // staging: thread -> row tid>>3 of each 64-row group, 16B at pre-swizzled col
    const int srow = tid >> 3;
    const int scol = (((tid & 7) ^ (srow & 7)) << 3);
    const ushort* Agbase = A  + (size_t)(brow + srow) * K_TOT + scol;
    const ushort* Bgbase = Bt + (size_t)(bcol + srow) * K_TOT + scol;

    const int ab = wmr * 128 + r;       // wave's A row base

    f32x4 acc[8][4];
    const f32x4 zero = {0.f, 0.f, 0.f, 0.f};
    #pragma unroll
    for (int i = 0; i < 8; ++i)
        #pragma unroll
        for (int j = 0; j < 4; ++j) acc[i][j] = zero;

    // ---- prologue: A(0)+B(0)+B(1); vmcnt(4) drains A(0)+B(0), keeps B(1);
    //      preload bg(0) (retired by tile0 p0's lgkm(4)) ----
    STAGE_A2(0, 0, 0) STAGE_A2(0, 1, 0)
    STAGE_B2(0, 0, 0) STAGE_B2(0, 1, 0)
    STAGE_B2(1, 0, 1) STAGE_B2(1, 1, 1)
    asm volatile("s_waitcnt vmcnt(4)" ::: "memory");
    __builtin_amdgcn_s_barrier();

    bf16x8 afX[4], afY[4];
    bf16x8 bg[4][2];
    RD_BG(0)
    __builtin_amdgcn_sched_barrier(0);

    for (int t = 0; t < NT - 2; t += 2) {
        TILE_BODY(0, t,     1, 1, 1, 4, 4)
        TILE_BODY(1, t + 1, 1, 1, 1, 4, 4)
    }
    TILE_BODY(0, NT - 2, 1, 0, 1, 4, 0)    // stage A(31); bg(31); p3 drains all
    TILE_BODY(1, NT - 1, 0, 0, 0, -1, -1)  // pure compute

    // ---- epilogue: bias + store (C/D layout: col=lane&15, row=(lane>>4)*4+reg)
    const int hq = (lane >> 4) * 4;
    float bv[4];
    #pragma unroll
    for (int j = 0; j < 4; ++j) bv[j] = bias[bcol + wcn * 64 + j * 16 + r];
    #pragma unroll
    for (int i = 0; i < 8; ++i) {
        const int row0 = brow + wmr * 128 + i * 16 + hq;
        #pragma unroll
        for (int j = 0; j < 4; ++j) {
            const int col = bcol + wcn * 64 + j * 16 + r;
            #pragma unroll
            for (int jj = 0; jj < 4; ++jj)
                C[(size_t)(row0 + jj) * N_TOT + col] = acc[i][j][jj] + bv[j];
        }
    }
}

extern "C" void kernel_launch(void* const* d_in, const int* in_sizes, int n_in,
                              void* d_out, int out_size, void* d_ws, size_t ws_size,
                              hipStream_t stream) {
    const float* x    = (const float*)d_in[0];   // [4,4096,2048]
    const float* wgt  = (const float*)d_in[1];   // [2048,2048]
    const float* bias = (const float*)d_in[2];   // [2048]
    float* out = (float*)d_out;                  // [4,4096,2048]

    ushort* qx = (ushort*)d_ws;                          // 64 MB
    ushort* qw = qx + (size_t)M_TOT * K_TOT;             // 8 MB

    quant_x_kernel<<<(M_TOT * K_TOT / 4) / 256, 256, 0, stream>>>(x, qx);
    quant_w_kernel<<<(64 * 64 * 64) / 256, 256, 0, stream>>>(wgt, qw);
    gemm_pipe4_kernel<<<(M_TOT / 256) * (N_TOT / 256), 512, 0, stream>>>(qx, qw, bias, out);
}

// Round 9
// 165.295 us; speedup vs baseline: 1.1264x; 1.0309x over previous
//
#include <hip/hip_runtime.h>
#include <hip/hip_bf16.h>
#include <stdint.h>

#define M_TOT 16384
#define N_TOT 2048
#define K_TOT 2048
#define NT 32            // K-tiles of BK=64

typedef __attribute__((ext_vector_type(8))) short bf16x8;
typedef __attribute__((ext_vector_type(4))) float f32x4;

__device__ __forceinline__ ushort f32_to_bf16_rne(float f) {
    uint32_t u = __float_as_uint(f);
    uint32_t r = (u + 0x7fffu + ((u >> 16) & 1u)) >> 16;
    return (ushort)r;
}

__device__ __forceinline__ void async_copy16(const void* gptr, void* lptr) {
    __builtin_amdgcn_global_load_lds(
        (const __attribute__((address_space(1))) uint32_t*)gptr,
        (__attribute__((address_space(3))) uint32_t*)lptr,
        16, 0, 0);
}

// ---------------------------------------------------------------------------
// Fake-quantize x: per (row, 32-col) block, symmetric int8 -> bf16.
// ---------------------------------------------------------------------------
__global__ void quant_x_kernel(const float* __restrict__ x, ushort* __restrict__ qx) {
    const int tid = blockIdx.x * 256 + threadIdx.x;
    const float4 v = ((const float4*)x)[tid];
    float m = fmaxf(fmaxf(fabsf(v.x), fabsf(v.y)), fmaxf(fabsf(v.z), fabsf(v.w)));
    m = fmaxf(m, __shfl_xor(m, 1));
    m = fmaxf(m, __shfl_xor(m, 2));
    m = fmaxf(m, __shfl_xor(m, 4));
    const float s = (m > 0.f) ? (m / 127.f) : 1.f;
    const float q0 = fminf(fmaxf(rintf(v.x / s), -127.f), 127.f) * s;
    const float q1 = fminf(fmaxf(rintf(v.y / s), -127.f), 127.f) * s;
    const float q2 = fminf(fmaxf(rintf(v.z / s), -127.f), 127.f) * s;
    const float q3 = fminf(fmaxf(rintf(v.w / s), -127.f), 127.f) * s;
    ushort4 r;
    r.x = f32_to_bf16_rne(q0);
    r.y = f32_to_bf16_rne(q1);
    r.z = f32_to_bf16_rne(q2);
    r.w = f32_to_bf16_rne(q3);
    ((ushort4*)qx)[tid] = r;
}

// ---------------------------------------------------------------------------
// Fake-quantize weight (kept [Dout][Din] == B^T layout). 32x32 blocks.
// ---------------------------------------------------------------------------
__global__ void quant_w_kernel(const float* __restrict__ w, ushort* __restrict__ qw) {
    const int gtid = blockIdx.x * 256 + threadIdx.x;
    const int wid  = gtid >> 6;
    const int lane = gtid & 63;
    const int tn = wid >> 6;
    const int tk = wid & 63;
    const int row = tn * 32 + (lane >> 1);
    const int col = tk * 32 + ((lane & 1) << 4);
    const float* p = w + (size_t)row * K_TOT + col;
    const float4 v0 = ((const float4*)p)[0];
    const float4 v1 = ((const float4*)p)[1];
    const float4 v2 = ((const float4*)p)[2];
    const float4 v3 = ((const float4*)p)[3];
    float m = 0.f;
#define MAX4(V) m = fmaxf(m, fmaxf(fmaxf(fabsf(V.x), fabsf(V.y)), fmaxf(fabsf(V.z), fabsf(V.w))));
    MAX4(v0) MAX4(v1) MAX4(v2) MAX4(v3)
#undef MAX4
    #pragma unroll
    for (int off = 1; off < 64; off <<= 1) m = fmaxf(m, __shfl_xor(m, off));
    const float s = (m > 0.f) ? (m / 127.f) : 1.f;
    float vv[16] = {v0.x, v0.y, v0.z, v0.w, v1.x, v1.y, v1.z, v1.w,
                    v2.x, v2.y, v2.z, v2.w, v3.x, v3.y, v3.z, v3.w};
    union { ushort us[16]; uint4 q[2]; } o;
    #pragma unroll
    for (int i = 0; i < 16; ++i) {
        const float q = fminf(fmaxf(rintf(vv[i] / s), -127.f), 127.f) * s;
        o.us[i] = f32_to_bf16_rne(q);
    }
    uint4* dst = (uint4*)(qw + (size_t)row * K_TOT + col);
    dst[0] = o.q[0];
    dst[1] = o.q[1];
}

// ---------------------------------------------------------------------------
// 256x256 bf16 GEMM — R5 schedule with the mid-tile barrier REMOVED via
// B triple-buffering.  LDS: As[2] 64KB + Bs[3] 96KB = 160KB (1 block/CU).
// B(t) in slot t%3; B(t+2) staged into (t+2)%3 -> disjoint from all reads
// for any intra-tile wave skew -> no WAR fence.  ONE barrier per tile (p3,
// after vmcnt(4)).  Waves on a SIMD can skew phases, overlapping one wave's
// LDS bursts with the other's MFMA (T5 role-split).
// lgkm trace (per wave, unchanged from R5): p0 wait drains bg8+afX4 (leaves
// afY); p1 drains afY (leaves afX); p2 drains afX (leaves afY); p3 lgkm(0).
// vmcnt steady state at p3: 12 in flight -> vmcnt(4) drains B(t+1)+A(t+1),
// keeps B(t+2) in flight.
// ---------------------------------------------------------------------------
#define LDSA(tb, row, colus) \
    (*(const bf16x8*)&As[tb][row][(colus) ^ (((row) & 7) << 3)])
#define LDSB(slot, row, colus) \
    (*(const bf16x8*)&Bs[slot][row][(colus) ^ (((row) & 7) << 3)])

#define STAGE_A(tb, hh, li, tt)                                                          \
    async_copy16(Agbase + (size_t)((hh) * 128 + (li) * 64) * K_TOT + (size_t)(tt) * 64,  \
                 (char*)&As[0][0][0] + (tb) * 32768 + (hh) * 16384 + (li) * 8192 + (wv << 10));
#define STAGE_B(slot, hh, li, tt)                                                        \
    async_copy16(Bgbase + (size_t)((hh) * 128 + (li) * 64) * K_TOT + (size_t)(tt) * 64,  \
                 (char*)&Bs[0][0][0] + (size_t)(slot) * 32768 + (hh) * 16384 + (li) * 8192 + (wv << 10));
#define STAGE_A2(tb, hh, tt)    { STAGE_A(tb, hh, 0, tt) STAGE_A(tb, hh, 1, tt) }
#define STAGE_B2(slot, hh, tt)  { STAGE_B(slot, hh, 0, tt) STAGE_B(slot, hh, 1, tt) }

#define WAITLGKM4 { asm volatile("s_waitcnt lgkmcnt(4)" ::: "memory"); __builtin_amdgcn_sched_barrier(0); }
#define WAITLGKM0 { asm volatile("s_waitcnt lgkmcnt(0)" ::: "memory"); __builtin_amdgcn_sched_barrier(0); }

// read the 4 A-fragments of row-pair q (rows q*32, q*32+16; k lo/hi halves)
#define RD_AF(DST, tb, q) {                                   \
    DST[0] = LDSA(tb, ab + (q) * 32,      h8);                \
    DST[1] = LDSA(tb, ab + (q) * 32,      32 + h8);           \
    DST[2] = LDSA(tb, ab + (q) * 32 + 16, h8);                \
    DST[3] = LDSA(tb, ab + (q) * 32 + 16, 32 + h8); }

#define RD_BG(slot) {                                                         \
    _Pragma("unroll")                                                         \
    for (int j = 0; j < 4; ++j) {                                             \
        const int bb = wcn * 64 + j * 16 + r;                                 \
        bg[j][0] = LDSB(slot, bb, h8);  bg[j][1] = LDSB(slot, bb, 32 + h8);   \
    } }

#define MFMA_PH(i0, AF)                                                                   \
    __builtin_amdgcn_s_setprio(1);                                                        \
    _Pragma("unroll")                                                                     \
    for (int j = 0; j < 4; ++j) {                                                         \
        acc[i0][j]     = __builtin_amdgcn_mfma_f32_16x16x32_bf16(AF[0], bg[j][0], acc[i0][j], 0, 0, 0);     \
        acc[i0][j]     = __builtin_amdgcn_mfma_f32_16x16x32_bf16(AF[1], bg[j][1], acc[i0][j], 0, 0, 0);     \
        acc[(i0)+1][j] = __builtin_amdgcn_mfma_f32_16x16x32_bf16(AF[2], bg[j][0], acc[(i0)+1][j], 0, 0, 0); \
        acc[(i0)+1][j] = __builtin_amdgcn_mfma_f32_16x16x32_bf16(AF[3], bg[j][1], acc[(i0)+1][j], 0, 0, 0); \
    }                                                                                     \
    __builtin_amdgcn_s_setprio(0);

// One K-tile.  tb = t&1 (A buffer).  BRD: B read slot (t%3); BWR: B stage
// slot ((t+2)%3).  STA/STB gate staging; VMC: 4 / 0 / -1 (skip).
#define TILE_BODY(tb, t, STA, STB, VMC, BRD, BWR)                                         \
  {                                                                                       \
    /* -- p0: afX(q0) + bg(8) + afY(q1); stage A(t+1)h0; drain afX+bg -- */               \
    RD_AF(afX, tb, 0)                                                                     \
    RD_BG(BRD)                                                                            \
    RD_AF(afY, tb, 1)                                                                     \
    if (STA) STAGE_A2(tb ^ 1, 0, (t) + 1)                                                 \
    WAITLGKM4                                                                             \
    MFMA_PH(0, afX)                                                                       \
    /* -- p1: afX(q2); stage A(t+1)h1; drain afY -- */                                    \
    RD_AF(afX, tb, 2)                                                                     \
    if (STA) STAGE_A2(tb ^ 1, 1, (t) + 1)                                                 \
    WAITLGKM4                                                                             \
    MFMA_PH(2, afY)                                                                       \
    /* -- p2: afY(q3); stage B(t+2)h0 into disjoint slot; drain afX -- */                 \
    RD_AF(afY, tb, 3)                                                                     \
    if (STB) STAGE_B2(BWR, 0, (t) + 2)                                                    \
    WAITLGKM4                                                                             \
    MFMA_PH(4, afX)                                                                       \
    /* -- p3: stage B(t+2)h1; drain afY; counted vmcnt; sole barrier -- */                \
    if (STB) STAGE_B2(BWR, 1, (t) + 2)                                                    \
    WAITLGKM0                                                                             \
    MFMA_PH(6, afY)                                                                       \
    if ((VMC) == 4)      { asm volatile("s_waitcnt vmcnt(4)" ::: "memory"); }             \
    else if ((VMC) == 0) { asm volatile("s_waitcnt vmcnt(0)" ::: "memory"); }             \
    __builtin_amdgcn_s_barrier();  /* staged A(t+1)/B(t+1) collectively visible */        \
  }

__global__ __launch_bounds__(512, 2) void gemm_pipe5_kernel(
    const ushort* __restrict__ A,    // [M][K] bf16 bits
    const ushort* __restrict__ Bt,   // [N][K] bf16 bits
    const float* __restrict__ bias,  // [N]
    float* __restrict__ C) {         // [M][N]

    __shared__ ushort As[2][256][64];   // 64 KB
    __shared__ ushort Bs[3][256][64];   // 96 KB (triple-buffered B)

    const int tid  = threadIdx.x;
    const int lane = tid & 63;
    const int wv   = tid >> 6;          // wave 0..7
    const int wmr  = wv >> 2;           // 0..1  (M)
    const int wcn  = wv & 3;            // 0..3  (N)
    const int r    = lane & 15;
    const int h8   = (lane >> 4) << 3;  // 0,8,16,24 (ushort col of k-frag)

    // bijective XCD swizzle (nwg = 512)
    const int nbn  = N_TOT / 256;                 // 8
    const int nwg  = (M_TOT / 256) * nbn;         // 512
    const int cpx  = nwg >> 3;
    const int swz  = (blockIdx.x & 7) * cpx + (blockIdx.x >> 3);
    const int brow = (swz / nbn) * 256;
    const int bcol = (swz % nbn) * 256;

    // staging: thread -> row tid>>3 of each 64-row group, 16B at pre-swizzled col
    const int srow = tid >> 3;
    const int scol = (((tid & 7) ^ (srow & 7)) << 3);
    const ushort* Agbase = A  + (size_t)(brow + srow) * K_TOT + scol;
    const ushort* Bgbase = Bt + (size_t)(bcol + srow) * K_TOT + scol;

    const int ab = wmr * 128 + r;       // wave's A row base

    f32x4 acc[8][4];
    const f32x4 zero = {0.f, 0.f, 0.f, 0.f};
    #pragma unroll
    for (int i = 0; i < 8; ++i)
        #pragma unroll
        for (int j = 0; j < 4; ++j) acc[i][j] = zero;

    // ---- prologue: A(0)->As0, B(0)->slot0, B(1)->slot1; vmcnt(4) keeps B(1)
    //      in flight; barrier ----
    STAGE_A2(0, 0, 0) STAGE_A2(0, 1, 0)
    STAGE_B2(0, 0, 0) STAGE_B2(0, 1, 0)
    STAGE_B2(1, 0, 1) STAGE_B2(1, 1, 1)
    asm volatile("s_waitcnt vmcnt(4)" ::: "memory");
    __builtin_amdgcn_s_barrier();

    bf16x8 afX[4], afY[4];
    bf16x8 bg[4][2];

    int brd = 0;   // B read slot  = t%3
    int bwr = 2;   // B stage slot = (t+2)%3

    for (int t = 0; t < NT - 2; t += 2) {
        TILE_BODY(0, t,     1, 1, 4, brd, bwr)
        brd = (brd == 2) ? 0 : brd + 1;  bwr = (bwr == 2) ? 0 : bwr + 1;
        TILE_BODY(1, t + 1, 1, 1, 4, brd, bwr)
        brd = (brd == 2) ? 0 : brd + 1;  bwr = (bwr == 2) ? 0 : bwr + 1;
    }
    TILE_BODY(0, NT - 2, 1, 0, 0, brd, 0)    // stage A(31) only; drain all
    brd = (brd == 2) ? 0 : brd + 1;
    TILE_BODY(1, NT - 1, 0, 0, -1, brd, 0)   // pure compute

    // ---- epilogue: bias + store (C/D layout: col=lane&15, row=(lane>>4)*4+reg)
    const int hq = (lane >> 4) * 4;
    float bv[4];
    #pragma unroll
    for (int j = 0; j < 4; ++j) bv[j] = bias[bcol + wcn * 64 + j * 16 + r];
    #pragma unroll
    for (int i = 0; i < 8; ++i) {
        const int row0 = brow + wmr * 128 + i * 16 + hq;
        #pragma unroll
        for (int j = 0; j < 4; ++j) {
            const int col = bcol + wcn * 64 + j * 16 + r;
            #pragma unroll
            for (int jj = 0; jj < 4; ++jj)
                C[(size_t)(row0 + jj) * N_TOT + col] = acc[i][j][jj] + bv[j];
        }
    }
}

extern "C" void kernel_launch(void* const* d_in, const int* in_sizes, int n_in,
                              void* d_out, int out_size, void* d_ws, size_t ws_size,
                              hipStream_t stream) {
    const float* x    = (const float*)d_in[0];   // [4,4096,2048]
    const float* wgt  = (const float*)d_in[1];   // [2048,2048]
    const float* bias = (const float*)d_in[2];   // [2048]
    float* out = (float*)d_out;                  // [4,4096,2048]

    ushort* qx = (ushort*)d_ws;                          // 64 MB
    ushort* qw = qx + (size_t)M_TOT * K_TOT;             // 8 MB

    quant_x_kernel<<<(M_TOT * K_TOT / 4) / 256, 256, 0, stream>>>(x, qx);
    quant_w_kernel<<<(64 * 64 * 64) / 256, 256, 0, stream>>>(wgt, qw);
    gemm_pipe5_kernel<<<(M_TOT / 256) * (N_TOT / 256), 512, 0, stream>>>(qx, qw, bias, out);
}